// Round 4
// baseline (138.091 us; speedup 1.0000x reference)
//
#include <hip/hip_runtime.h>
#include <cmath>

constexpr int B = 8, S = 128, F = 512, D = 256, FEAT = 80;
// Finite stand-in for -inf (see round-1 note: avoids nan in harness absmax).
#define NEG_HUGE (-3.0e38f)

// ---------------- fused prep: gamma table + 5 weight transposes ----------------
constexpr int N_G  = 1024;
constexpr int N_T1 = D * D * 3;
constexpr int N_T2 = D * D;
constexpr int N_F1 = D * FEAT * 3;
constexpr int N_F2 = D * D * 3;
constexpr int N_F3 = D * D;
constexpr int PREP_TOTAL = N_G + N_T1 + N_T2 + N_F1 + N_F2 + N_F3;

__device__ __forceinline__ void transpose_elem(const float* __restrict__ in,
                                               float* __restrict__ out,
                                               int O, int I, int K, int idx) {
    // out[(k*I + i)*O + o] = in[(o*I + i)*K + k]
    int o = idx % O;
    int rest = idx / O;
    int i = rest % I;
    int k = rest / I;
    out[idx] = in[(o * I + i) * K + k];
}

__global__ __launch_bounds__(256) void k_prep(
    const float* __restrict__ tw1, const float* __restrict__ tw2,
    const float* __restrict__ fw1, const float* __restrict__ fw2,
    const float* __restrict__ fw3,
    float* __restrict__ gt, float* __restrict__ tw1t, float* __restrict__ tw2t,
    float* __restrict__ fw1t, float* __restrict__ fw2t, float* __restrict__ fw3t)
{
    int idx = blockIdx.x * 256 + threadIdx.x;
    if (idx < N_G) { gt[idx] = (float)lgamma((double)idx); return; }
    idx -= N_G;
    if (idx < N_T1) { transpose_elem(tw1, tw1t, D, D, 3, idx); return; }
    idx -= N_T1;
    if (idx < N_T2) { transpose_elem(tw2, tw2t, D, D, 1, idx); return; }
    idx -= N_T2;
    if (idx < N_F1) { transpose_elem(fw1, fw1t, D, FEAT, 3, idx); return; }
    idx -= N_F1;
    if (idx < N_F2) { transpose_elem(fw2, fw2t, D, D, 3, idx); return; }
    idx -= N_F2;
    if (idx < N_F3) { transpose_elem(fw3, fw3t, D, D, 1, idx); return; }
}

// ---------------- fused text + feat conv stacks ----------------
// Feat tile FT=8: LDS = ms[12][80] + y1t[256][12] + y2t[256][8]
//               = 960 + 3072 + 2048 = 6080 floats = 23.75 KB -> 3+ blocks/CU.
constexpr int FT = 8;
constexpr int NFB = B * (F / FT);    // 512 feat blocks
constexpr int ST = 4;
constexpr int NTB = B * (S / ST);    // 256 text blocks
constexpr int LDS_FLOATS = 960 + 3072 + 2048;

__global__ __launch_bounds__(256) void k_stacks(
    const float* __restrict__ h, const float* __restrict__ m,
    const float* __restrict__ tw1t, const float* __restrict__ tb1,
    const float* __restrict__ tw2t, const float* __restrict__ tb2,
    const float* __restrict__ fw1t, const float* __restrict__ fb1,
    const float* __restrict__ fw2t, const float* __restrict__ fb2,
    const float* __restrict__ fw3t, const float* __restrict__ fb3,
    float* __restrict__ hh, float* __restrict__ mm)
{
    __shared__ float lds[LDS_FLOATS];
    int t = threadIdx.x;
    int bid = blockIdx.x;
    // Interleave: every 3rd block is text so each CU gets ~2 feat + 1 text.
    bool is_text = (bid % 3) == 2;

    if (!is_text) {
        // ================= feat path (FT=8) =================
        int fbid = (bid / 3) * 2 + (bid % 3);
        float* ms  = lds;                  // [12][FEAT]
        float* y1t = lds + 960;            // [256][12] ch-major
        float* y2t = lds + 960 + 3072;     // [256][8]  ch-major
        int b  = fbid / (F / FT);
        int f0 = (fbid % (F / FT)) * FT;

        for (int i = t; i < 12 * FEAT; i += 256) {
            int p = i / FEAT, e = i % FEAT;
            int f = f0 - 2 + p;
            ms[p * FEAT + e] = (f >= 0 && f < F) ? m[(b * F + f) * FEAT + e] : 0.f;
        }
        __syncthreads();

        // ---- stage 1 (K=3, FEAT->D): thread = out channel t, 10 positions
        {
            float acc[10];
            float bias = fb1[t];
#pragma unroll
            for (int r = 0; r < 10; ++r) acc[r] = bias;
            for (int e0 = 0; e0 < FEAT; e0 += 2) {
                float2 a[12];
#pragma unroll
                for (int p = 0; p < 12; ++p) a[p] = *(const float2*)&ms[p * FEAT + e0];
                float2 w[3];
#pragma unroll
                for (int k = 0; k < 3; ++k) {
                    w[k].x = fw1t[(k * FEAT + e0    ) * D + t];
                    w[k].y = fw1t[(k * FEAT + e0 + 1) * D + t];
                }
#pragma unroll
                for (int r = 0; r < 10; ++r)
#pragma unroll
                    for (int k = 0; k < 3; ++k)
                        acc[r] = fmaf(w[k].x, a[r + k].x, fmaf(w[k].y, a[r + k].y, acc[r]));
            }
#pragma unroll
            for (int r = 0; r < 10; r += 2) {
                float2 v = { fmaxf(acc[r], 0.f), fmaxf(acc[r + 1], 0.f) };
                *(float2*)&y1t[t * 12 + r] = v;
            }
        }
        __syncthreads();

        int c0 = (t & 63) * 4;      // 4 output channels
        int q0 = (t >> 6) * 2;      // 2 positions (q0 in {0,2,4,6})

        // ---- stage 2 (K=3, D->D): thread = 4ch x 2pos
        {
            float4 bias = *(const float4*)&fb2[c0];
            float acc[2][4];
#pragma unroll
            for (int q = 0; q < 2; ++q) {
                acc[q][0] = bias.x; acc[q][1] = bias.y; acc[q][2] = bias.z; acc[q][3] = bias.w;
            }
            for (int cp = 0; cp < D; ++cp) {
                float2 a0 = *(const float2*)&y1t[cp * 12 + q0];       // wave-uniform
                float2 a1 = *(const float2*)&y1t[cp * 12 + q0 + 2];
                float a[4] = { a0.x, a0.y, a1.x, a1.y };
#pragma unroll
                for (int k = 0; k < 3; ++k) {
                    float4 w = *(const float4*)&fw2t[(k * D + cp) * D + c0];
#pragma unroll
                    for (int q = 0; q < 2; ++q) {
                        acc[q][0] = fmaf(w.x, a[q + k], acc[q][0]);
                        acc[q][1] = fmaf(w.y, a[q + k], acc[q][1]);
                        acc[q][2] = fmaf(w.z, a[q + k], acc[q][2]);
                        acc[q][3] = fmaf(w.w, a[q + k], acc[q][3]);
                    }
                }
            }
#pragma unroll
            for (int j = 0; j < 4; ++j) {
                float2 v = { fmaxf(acc[0][j], 0.f), fmaxf(acc[1][j], 0.f) };
                *(float2*)&y2t[(c0 + j) * 8 + q0] = v;
            }
        }
        __syncthreads();

        // ---- stage 3 (K=1, D->D)
        {
            float4 bias = *(const float4*)&fb3[c0];
            float acc[2][4];
#pragma unroll
            for (int q = 0; q < 2; ++q) {
                acc[q][0] = bias.x; acc[q][1] = bias.y; acc[q][2] = bias.z; acc[q][3] = bias.w;
            }
            for (int cp = 0; cp < D; ++cp) {
                float2 a = *(const float2*)&y2t[cp * 8 + q0];          // wave-uniform
                float4 w = *(const float4*)&fw3t[cp * D + c0];
                acc[0][0] = fmaf(w.x, a.x, acc[0][0]);
                acc[0][1] = fmaf(w.y, a.x, acc[0][1]);
                acc[0][2] = fmaf(w.z, a.x, acc[0][2]);
                acc[0][3] = fmaf(w.w, a.x, acc[0][3]);
                acc[1][0] = fmaf(w.x, a.y, acc[1][0]);
                acc[1][1] = fmaf(w.y, a.y, acc[1][1]);
                acc[1][2] = fmaf(w.z, a.y, acc[1][2]);
                acc[1][3] = fmaf(w.w, a.y, acc[1][3]);
            }
#pragma unroll
            for (int q = 0; q < 2; ++q) {
                float4 v = { acc[q][0], acc[q][1], acc[q][2], acc[q][3] };
                *(float4*)&mm[(b * F + f0 + q0 + q) * D + c0] = v;
            }
        }
    } else {
        // ================= text path =================
        int tb = bid / 3;
        int b  = tb / (S / ST);
        int s0 = (tb % (S / ST)) * ST;
        float* hs = lds;               // [6][D]
        float* x1 = lds + 6 * D;       // [4][D]

        for (int i = t; i < 6 * D; i += 256) {
            int r = i / D, e = i % D;
            int s = s0 - 1 + r;
            hs[r * D + e] = (s >= 0 && s < S) ? h[(b * S + s) * D + e] : 0.f;
        }
        __syncthreads();

        // ---- stage 1 (K=3, D->D): thread = out channel t, 4 positions
        {
            float acc[4];
            float bias = tb1[t];
#pragma unroll
            for (int r = 0; r < 4; ++r) acc[r] = bias;
            for (int e0 = 0; e0 < D; e0 += 2) {
                float2 a[6];
#pragma unroll
                for (int p = 0; p < 6; ++p) a[p] = *(const float2*)&hs[p * D + e0];
                float2 w[3];
#pragma unroll
                for (int k = 0; k < 3; ++k) {
                    w[k].x = tw1t[(k * D + e0    ) * D + t];
                    w[k].y = tw1t[(k * D + e0 + 1) * D + t];
                }
#pragma unroll
                for (int r = 0; r < 4; ++r)
#pragma unroll
                    for (int k = 0; k < 3; ++k)
                        acc[r] = fmaf(w[k].x, a[r + k].x, fmaf(w[k].y, a[r + k].y, acc[r]));
            }
#pragma unroll
            for (int r = 0; r < 4; ++r) x1[r * D + t] = fmaxf(acc[r], 0.f);
        }
        __syncthreads();

        // ---- stage 2 (K=1, D->D): thread = 4ch x 1pos
        {
            int c0 = (t & 63) * 4;
            int pg = t >> 6;
            float4 bias = *(const float4*)&tb2[c0];
            float acc[4] = { bias.x, bias.y, bias.z, bias.w };
            for (int cp0 = 0; cp0 < D; cp0 += 4) {
                float4 ax = *(const float4*)&x1[pg * D + cp0];
                float av[4] = { ax.x, ax.y, ax.z, ax.w };
#pragma unroll
                for (int i = 0; i < 4; ++i) {
                    float4 w = *(const float4*)&tw2t[(cp0 + i) * D + c0];
                    acc[0] = fmaf(w.x, av[i], acc[0]);
                    acc[1] = fmaf(w.y, av[i], acc[1]);
                    acc[2] = fmaf(w.z, av[i], acc[2]);
                    acc[3] = fmaf(w.w, av[i], acc[3]);
                }
            }
            float4 v = { acc[0], acc[1], acc[2], acc[3] };
            *(float4*)&hh[(b * S + s0 + pg) * D + c0] = v;
        }
    }
}

// ---------------- pairwise L2 distance ----------------
constexpr int TS = 32, TF = 64, TK = 32;
__global__ __launch_bounds__(256) void k_dist(
    const float* __restrict__ hh, const float* __restrict__ mm,
    float* __restrict__ scores)
{
    __shared__ float As[TS][TK + 1];
    __shared__ float Bs[TF][TK + 1];
    int t = threadIdx.x;
    constexpr int nf = F / TF;
    constexpr int ns = S / TS;
    int b = blockIdx.x / (nf * ns);
    int rem = blockIdx.x % (nf * ns);
    int s0 = (rem / nf) * TS;
    int f0 = (rem % nf) * TF;
    int tx = t & 15, ty = t >> 4;

    float c[2][4] = {};
    for (int k0 = 0; k0 < D; k0 += TK) {
        {
            int r = t / 8, c4 = (t % 8) * 4;
            float4 v = *(const float4*)&hh[(b * S + s0 + r) * D + k0 + c4];
            As[r][c4] = v.x; As[r][c4 + 1] = v.y; As[r][c4 + 2] = v.z; As[r][c4 + 3] = v.w;
        }
#pragma unroll
        for (int half = 0; half < 2; ++half) {
            int rr = half * 32 + t / 8, c4 = (t % 8) * 4;
            float4 v = *(const float4*)&mm[(b * F + f0 + rr) * D + k0 + c4];
            Bs[rr][c4] = v.x; Bs[rr][c4 + 1] = v.y; Bs[rr][c4 + 2] = v.z; Bs[rr][c4 + 3] = v.w;
        }
        __syncthreads();
#pragma unroll
        for (int k = 0; k < TK; ++k) {
            float a0 = As[ty * 2 + 0][k];
            float a1 = As[ty * 2 + 1][k];
            float b0 = Bs[tx * 4 + 0][k];
            float b1 = Bs[tx * 4 + 1][k];
            float b2 = Bs[tx * 4 + 2][k];
            float b3 = Bs[tx * 4 + 3][k];
            float d;
            d = a0 - b0; c[0][0] = fmaf(d, d, c[0][0]);
            d = a0 - b1; c[0][1] = fmaf(d, d, c[0][1]);
            d = a0 - b2; c[0][2] = fmaf(d, d, c[0][2]);
            d = a0 - b3; c[0][3] = fmaf(d, d, c[0][3]);
            d = a1 - b0; c[1][0] = fmaf(d, d, c[1][0]);
            d = a1 - b1; c[1][1] = fmaf(d, d, c[1][1]);
            d = a1 - b2; c[1][2] = fmaf(d, d, c[1][2]);
            d = a1 - b3; c[1][3] = fmaf(d, d, c[1][3]);
        }
        __syncthreads();
    }
#pragma unroll
    for (int i = 0; i < 2; ++i) {
        int s = s0 + ty * 2 + i;
        float4 v;
        v.x = -sqrtf(fmaxf(c[i][0], 0.f));
        v.y = -sqrtf(fmaxf(c[i][1], 0.f));
        v.z = -sqrtf(fmaxf(c[i][2], 0.f));
        v.w = -sqrtf(fmaxf(c[i][3], 0.f));
        *(float4*)&scores[(b * S + s) * F + f0 + tx * 4] = v;
    }
}

// ---------------- softmax over S + beta-binomial prior (in-place on d_out) ----------------
__global__ __launch_bounds__(256) void k_soft(
    const float* __restrict__ gt,
    const int* __restrict__ tok_len, const int* __restrict__ feat_len,
    float* __restrict__ out)
{
    __shared__ float gts[1024];
    __shared__ float red[256];
    int t = threadIdx.x;
    int b = blockIdx.x / (F / 64);
    int f0 = (blockIdx.x % (F / 64)) * 64;
    int fi = t & 63, sg = t >> 6;
    int f = f0 + fi;
    for (int i = t; i < 1024; i += 256) gts[i] = gt[i];
    int L = tok_len[b], Fl = feat_len[b];

    float sv[32];
    float mx = -INFINITY;
#pragma unroll
    for (int i = 0; i < 32; ++i) {
        int s = sg + i * 4;
        float v = out[(b * S + s) * F + f];
        if (s >= L) v = -INFINITY;
        sv[i] = v;
        mx = fmaxf(mx, v);
    }
    red[t] = mx;
    __syncthreads();
    float m = fmaxf(fmaxf(red[fi], red[64 + fi]), fmaxf(red[128 + fi], red[192 + fi]));
    __syncthreads();
    float sum = 0.f;
#pragma unroll
    for (int i = 0; i < 32; ++i) sum += expf(sv[i] - m);
    red[t] = sum;
    __syncthreads();
    float tot = red[fi] + red[64 + fi] + red[128 + fi] + red[192 + fi];
    float lse = m + logf(tot);

    float cb = gts[L] - gts[L + Fl] + gts[Fl + 1];
    bool fvalid = f < Fl;
    float cf = fvalid ? (-gts[f + 1] - gts[Fl - f]) : 0.f;
#pragma unroll
    for (int i = 0; i < 32; ++i) {
        int s = sg + i * 4;
        float o;
        if (s >= L || !fvalid) {
            o = NEG_HUGE;
        } else {
            float lp = cb + cf - gts[s + 1] - gts[L - s]
                     + gts[s + f + 1] + gts[L - 1 - s + Fl - f];
            o = lp + sv[i] - lse;
        }
        out[(b * S + s) * F + f] = o;
    }
}

extern "C" void kernel_launch(void* const* d_in, const int* in_sizes, int n_in,
                              void* d_out, int out_size, void* d_ws, size_t ws_size,
                              hipStream_t stream)
{
    const float* h   = (const float*)d_in[0];
    const float* m_  = (const float*)d_in[1];
    const float* tw1 = (const float*)d_in[2];
    const float* tb1 = (const float*)d_in[3];
    const float* tw2 = (const float*)d_in[4];
    const float* tb2 = (const float*)d_in[5];
    const float* fw1 = (const float*)d_in[6];
    const float* fb1 = (const float*)d_in[7];
    const float* fw2 = (const float*)d_in[8];
    const float* fb2 = (const float*)d_in[9];
    const float* fw3 = (const float*)d_in[10];
    const float* fb3 = (const float*)d_in[11];
    const int* tokl  = (const int*)d_in[13];
    const int* featl = (const int*)d_in[14];

    float* ws    = (float*)d_ws;
    float* gt    = ws;
    float* tw1t  = gt   + 1024;
    float* tw2t  = tw1t + N_T1;
    float* fw1t  = tw2t + N_T2;
    float* fw2t  = fw1t + N_F1;
    float* fw3t  = fw2t + N_F2;
    float* hh    = fw3t + N_F3;
    float* mm    = hh   + B * S * D;
    float* out   = (float*)d_out;

    k_prep<<<(PREP_TOTAL + 255) / 256, 256, 0, stream>>>(
        tw1, tw2, fw1, fw2, fw3, gt, tw1t, tw2t, fw1t, fw2t, fw3t);

    k_stacks<<<NFB + NTB, 256, 0, stream>>>(
        h, m_, tw1t, tb1, tw2t, tb2, fw1t, fb1, fw2t, fb2, fw3t, fb3, hh, mm);

    k_dist<<<B * (S / TS) * (F / TF), 256, 0, stream>>>(hh, mm, out);
    k_soft<<<B * (F / 64), 256, 0, stream>>>(gt, tokl, featl, out);
}

// Round 5
// 118.846 us; speedup vs baseline: 1.1619x; 1.1619x over previous
//
#include <hip/hip_runtime.h>
#include <cmath>

constexpr int B = 8, S = 128, F = 512, D = 256, FEAT = 80;
// Finite stand-in for -inf (see round-1 note: avoids nan in harness absmax).
#define NEG_HUGE (-3.0e38f)

// ---------------- fused prep: gamma table + 5 weight transposes ----------------
constexpr int N_G  = 1024;
constexpr int N_T1 = D * D * 3;
constexpr int N_T2 = D * D;
constexpr int N_F1 = D * FEAT * 3;
constexpr int N_F2 = D * D * 3;
constexpr int N_F3 = D * D;
constexpr int PREP_TOTAL = N_G + N_T1 + N_T2 + N_F1 + N_F2 + N_F3;

__device__ __forceinline__ void transpose_elem(const float* __restrict__ in,
                                               float* __restrict__ out,
                                               int O, int I, int K, int idx) {
    // out[(k*I + i)*O + o] = in[(o*I + i)*K + k]
    int o = idx % O;
    int rest = idx / O;
    int i = rest % I;
    int k = rest / I;
    out[idx] = in[(o * I + i) * K + k];
}

__global__ __launch_bounds__(256) void k_prep(
    const float* __restrict__ tw1, const float* __restrict__ tw2,
    const float* __restrict__ fw1, const float* __restrict__ fw2,
    const float* __restrict__ fw3,
    float* __restrict__ gt, float* __restrict__ tw1t, float* __restrict__ tw2t,
    float* __restrict__ fw1t, float* __restrict__ fw2t, float* __restrict__ fw3t)
{
    int idx = blockIdx.x * 256 + threadIdx.x;
    if (idx < N_G) { gt[idx] = (float)lgamma((double)idx); return; }
    idx -= N_G;
    if (idx < N_T1) { transpose_elem(tw1, tw1t, D, D, 3, idx); return; }
    idx -= N_T1;
    if (idx < N_T2) { transpose_elem(tw2, tw2t, D, D, 1, idx); return; }
    idx -= N_T2;
    if (idx < N_F1) { transpose_elem(fw1, fw1t, D, FEAT, 3, idx); return; }
    idx -= N_F1;
    if (idx < N_F2) { transpose_elem(fw2, fw2t, D, D, 3, idx); return; }
    idx -= N_F2;
    if (idx < N_F3) { transpose_elem(fw3, fw3t, D, D, 1, idx); return; }
}

// ---------------- fused text + feat conv stacks ----------------
// Thread = output channel everywhere; positions live in acc registers.
// Feat LDS: ms[12][80]=960 + y1t[256][12]=3072 + y2t[256][8]=2048 = 6080 fl = 24.3KB
constexpr int FT = 8;
constexpr int NFB = B * (F / FT);    // 512 feat blocks
constexpr int ST = 4;
constexpr int NTB = B * (S / ST);    // 256 text blocks
constexpr int LDS_FLOATS = 960 + 3072 + 2048;

__global__ __launch_bounds__(256) void k_stacks(
    const float* __restrict__ h, const float* __restrict__ m,
    const float* __restrict__ tw1t, const float* __restrict__ tb1,
    const float* __restrict__ tw2t, const float* __restrict__ tb2,
    const float* __restrict__ fw1t, const float* __restrict__ fb1,
    const float* __restrict__ fw2t, const float* __restrict__ fb2,
    const float* __restrict__ fw3t, const float* __restrict__ fb3,
    float* __restrict__ hh, float* __restrict__ mm)
{
    __shared__ float lds[LDS_FLOATS];
    int t = threadIdx.x;
    int bid = blockIdx.x;
    bool is_text = (bid % 3) == 2;   // interleave so each CU gets ~2 feat + 1 text

    if (!is_text) {
        // ================= feat path (FT=8, thread=channel) =================
        int fbid = (bid / 3) * 2 + (bid % 3);
        float* ms  = lds;               // [12][FEAT]
        float* y1t = lds + 960;         // [256][12] (10 valid, stride 12 => 16B-aligned rows)
        float* y2t = lds + 960 + 3072;  // [256][8]
        int b  = fbid / (F / FT);
        int f0 = (fbid % (F / FT)) * FT;

        for (int i = t; i < 12 * FEAT; i += 256) {
            int p = i / FEAT, e = i % FEAT;
            int f = f0 - 2 + p;
            ms[i] = (f >= 0 && f < F) ? m[(b * F + f) * FEAT + e] : 0.f;
        }
        __syncthreads();

        // ---- stage 1 (K=3, FEAT->D): out channel t, 10 positions (f0-1..f0+8)
        {
            float acc[10];
            float bias = fb1[t];
#pragma unroll
            for (int r = 0; r < 10; ++r) acc[r] = bias;
            for (int e0 = 0; e0 < FEAT; e0 += 4) {
                float4 a[12];
#pragma unroll
                for (int p = 0; p < 12; ++p) a[p] = *(const float4*)&ms[p * FEAT + e0];
                float w[3][4];
#pragma unroll
                for (int k = 0; k < 3; ++k)
#pragma unroll
                    for (int j = 0; j < 4; ++j)
                        w[k][j] = fw1t[(k * FEAT + e0 + j) * D + t];
#pragma unroll
                for (int r = 0; r < 10; ++r)
#pragma unroll
                    for (int k = 0; k < 3; ++k) {
                        acc[r] = fmaf(w[k][0], a[r + k].x, acc[r]);
                        acc[r] = fmaf(w[k][1], a[r + k].y, acc[r]);
                        acc[r] = fmaf(w[k][2], a[r + k].z, acc[r]);
                        acc[r] = fmaf(w[k][3], a[r + k].w, acc[r]);
                    }
            }
#pragma unroll
            for (int r = 0; r < 10; r += 2) {
                float2 v = { fmaxf(acc[r], 0.f), fmaxf(acc[r + 1], 0.f) };
                *(float2*)&y1t[t * 12 + r] = v;
            }
        }
        __syncthreads();

        // ---- stage 2 (K=3, D->D): out channel t, 8 positions
        {
            float acc2[8];
            float bias = fb2[t];
#pragma unroll
            for (int q = 0; q < 8; ++q) acc2[q] = bias;
#pragma unroll 2
            for (int cp = 0; cp < D; ++cp) {
                float w0 = fw2t[(0 * D + cp) * D + t];
                float w1 = fw2t[(1 * D + cp) * D + t];
                float w2 = fw2t[(2 * D + cp) * D + t];
                float4 a0 = *(const float4*)&y1t[cp * 12 + 0];   // wave-uniform broadcast
                float4 a1 = *(const float4*)&y1t[cp * 12 + 4];
                float2 a2 = *(const float2*)&y1t[cp * 12 + 8];
                float a[10] = { a0.x, a0.y, a0.z, a0.w, a1.x, a1.y, a1.z, a1.w, a2.x, a2.y };
#pragma unroll
                for (int q = 0; q < 8; ++q)
                    acc2[q] = fmaf(w0, a[q], fmaf(w1, a[q + 1], fmaf(w2, a[q + 2], acc2[q])));
            }
#pragma unroll
            for (int q = 0; q < 8; q += 4) {
                float4 v = { fmaxf(acc2[q], 0.f), fmaxf(acc2[q + 1], 0.f),
                             fmaxf(acc2[q + 2], 0.f), fmaxf(acc2[q + 3], 0.f) };
                *(float4*)&y2t[t * 8 + q] = v;
            }
        }
        __syncthreads();

        // ---- stage 3 (K=1, D->D): out channel t, 8 positions
        {
            float acc3[8];
            float bias = fb3[t];
#pragma unroll
            for (int q = 0; q < 8; ++q) acc3[q] = bias;
#pragma unroll 4
            for (int cp = 0; cp < D; ++cp) {
                float w = fw3t[cp * D + t];
                float4 a0 = *(const float4*)&y2t[cp * 8 + 0];    // wave-uniform broadcast
                float4 a1 = *(const float4*)&y2t[cp * 8 + 4];
                acc3[0] = fmaf(w, a0.x, acc3[0]);
                acc3[1] = fmaf(w, a0.y, acc3[1]);
                acc3[2] = fmaf(w, a0.z, acc3[2]);
                acc3[3] = fmaf(w, a0.w, acc3[3]);
                acc3[4] = fmaf(w, a1.x, acc3[4]);
                acc3[5] = fmaf(w, a1.y, acc3[5]);
                acc3[6] = fmaf(w, a1.z, acc3[6]);
                acc3[7] = fmaf(w, a1.w, acc3[7]);
            }
#pragma unroll
            for (int q = 0; q < 8; ++q)
                mm[(b * F + f0 + q) * D + t] = acc3[q];
        }
    } else {
        // ================= text path (thread=channel) =================
        int tb = bid / 3;
        int b  = tb / (S / ST);
        int s0 = (tb % (S / ST)) * ST;
        float* hs  = lds;            // [6][D]
        float* x1t = lds + 6 * D;    // [256][4]

        for (int i = t; i < 6 * D; i += 256) {
            int r = i / D, e = i % D;
            int s = s0 - 1 + r;
            hs[i] = (s >= 0 && s < S) ? h[(b * S + s) * D + e] : 0.f;
        }
        __syncthreads();

        // ---- stage 1 (K=3, D->D): out channel t, 4 positions
        {
            float acc[4];
            float bias = tb1[t];
#pragma unroll
            for (int r = 0; r < 4; ++r) acc[r] = bias;
            for (int e0 = 0; e0 < D; e0 += 4) {
                float4 a[6];
#pragma unroll
                for (int p = 0; p < 6; ++p) a[p] = *(const float4*)&hs[p * D + e0];
                float w[3][4];
#pragma unroll
                for (int k = 0; k < 3; ++k)
#pragma unroll
                    for (int j = 0; j < 4; ++j)
                        w[k][j] = tw1t[(k * D + e0 + j) * D + t];
#pragma unroll
                for (int r = 0; r < 4; ++r)
#pragma unroll
                    for (int k = 0; k < 3; ++k) {
                        acc[r] = fmaf(w[k][0], a[r + k].x, acc[r]);
                        acc[r] = fmaf(w[k][1], a[r + k].y, acc[r]);
                        acc[r] = fmaf(w[k][2], a[r + k].z, acc[r]);
                        acc[r] = fmaf(w[k][3], a[r + k].w, acc[r]);
                    }
            }
            float4 v = { fmaxf(acc[0], 0.f), fmaxf(acc[1], 0.f),
                         fmaxf(acc[2], 0.f), fmaxf(acc[3], 0.f) };
            *(float4*)&x1t[t * 4] = v;
        }
        __syncthreads();

        // ---- stage 2 (K=1, D->D): out channel t, 4 positions
        {
            float acc2[4];
            float bias = tb2[t];
#pragma unroll
            for (int p = 0; p < 4; ++p) acc2[p] = bias;
#pragma unroll 4
            for (int cp = 0; cp < D; ++cp) {
                float w = tw2t[cp * D + t];
                float4 a = *(const float4*)&x1t[cp * 4];         // wave-uniform broadcast
                acc2[0] = fmaf(w, a.x, acc2[0]);
                acc2[1] = fmaf(w, a.y, acc2[1]);
                acc2[2] = fmaf(w, a.z, acc2[2]);
                acc2[3] = fmaf(w, a.w, acc2[3]);
            }
#pragma unroll
            for (int p = 0; p < 4; ++p)
                hh[(b * S + s0 + p) * D + t] = acc2[p];
        }
    }
}

// ---------------- pairwise L2 distance ----------------
constexpr int TS = 32, TF = 64, TK = 32;
__global__ __launch_bounds__(256) void k_dist(
    const float* __restrict__ hh, const float* __restrict__ mm,
    float* __restrict__ scores)
{
    __shared__ float As[TS][TK + 1];
    __shared__ float Bs[TF][TK + 1];
    int t = threadIdx.x;
    constexpr int nf = F / TF;
    constexpr int ns = S / TS;
    int b = blockIdx.x / (nf * ns);
    int rem = blockIdx.x % (nf * ns);
    int s0 = (rem / nf) * TS;
    int f0 = (rem % nf) * TF;
    int tx = t & 15, ty = t >> 4;

    float c[2][4] = {};
    for (int k0 = 0; k0 < D; k0 += TK) {
        {
            int r = t / 8, c4 = (t % 8) * 4;
            float4 v = *(const float4*)&hh[(b * S + s0 + r) * D + k0 + c4];
            As[r][c4] = v.x; As[r][c4 + 1] = v.y; As[r][c4 + 2] = v.z; As[r][c4 + 3] = v.w;
        }
#pragma unroll
        for (int half = 0; half < 2; ++half) {
            int rr = half * 32 + t / 8, c4 = (t % 8) * 4;
            float4 v = *(const float4*)&mm[(b * F + f0 + rr) * D + k0 + c4];
            Bs[rr][c4] = v.x; Bs[rr][c4 + 1] = v.y; Bs[rr][c4 + 2] = v.z; Bs[rr][c4 + 3] = v.w;
        }
        __syncthreads();
#pragma unroll
        for (int k = 0; k < TK; ++k) {
            float a0 = As[ty * 2 + 0][k];
            float a1 = As[ty * 2 + 1][k];
            float b0 = Bs[tx * 4 + 0][k];
            float b1 = Bs[tx * 4 + 1][k];
            float b2 = Bs[tx * 4 + 2][k];
            float b3 = Bs[tx * 4 + 3][k];
            float d;
            d = a0 - b0; c[0][0] = fmaf(d, d, c[0][0]);
            d = a0 - b1; c[0][1] = fmaf(d, d, c[0][1]);
            d = a0 - b2; c[0][2] = fmaf(d, d, c[0][2]);
            d = a0 - b3; c[0][3] = fmaf(d, d, c[0][3]);
            d = a1 - b0; c[1][0] = fmaf(d, d, c[1][0]);
            d = a1 - b1; c[1][1] = fmaf(d, d, c[1][1]);
            d = a1 - b2; c[1][2] = fmaf(d, d, c[1][2]);
            d = a1 - b3; c[1][3] = fmaf(d, d, c[1][3]);
        }
        __syncthreads();
    }
#pragma unroll
    for (int i = 0; i < 2; ++i) {
        int s = s0 + ty * 2 + i;
        float4 v;
        v.x = -sqrtf(fmaxf(c[i][0], 0.f));
        v.y = -sqrtf(fmaxf(c[i][1], 0.f));
        v.z = -sqrtf(fmaxf(c[i][2], 0.f));
        v.w = -sqrtf(fmaxf(c[i][3], 0.f));
        *(float4*)&scores[(b * S + s) * F + f0 + tx * 4] = v;
    }
}

// ---------------- softmax over S + beta-binomial prior (in-place on d_out) ----------------
__global__ __launch_bounds__(256) void k_soft(
    const float* __restrict__ gt,
    const int* __restrict__ tok_len, const int* __restrict__ feat_len,
    float* __restrict__ out)
{
    __shared__ float gts[1024];
    __shared__ float red[256];
    int t = threadIdx.x;
    int b = blockIdx.x / (F / 64);
    int f0 = (blockIdx.x % (F / 64)) * 64;
    int fi = t & 63, sg = t >> 6;
    int f = f0 + fi;
    for (int i = t; i < 1024; i += 256) gts[i] = gt[i];
    int L = tok_len[b], Fl = feat_len[b];

    float sv[32];
    float mx = -INFINITY;
#pragma unroll
    for (int i = 0; i < 32; ++i) {
        int s = sg + i * 4;
        float v = out[(b * S + s) * F + f];
        if (s >= L) v = -INFINITY;
        sv[i] = v;
        mx = fmaxf(mx, v);
    }
    red[t] = mx;
    __syncthreads();
    float m = fmaxf(fmaxf(red[fi], red[64 + fi]), fmaxf(red[128 + fi], red[192 + fi]));
    __syncthreads();
    float sum = 0.f;
#pragma unroll
    for (int i = 0; i < 32; ++i) sum += expf(sv[i] - m);
    red[t] = sum;
    __syncthreads();
    float tot = red[fi] + red[64 + fi] + red[128 + fi] + red[192 + fi];
    float lse = m + logf(tot);

    float cb = gts[L] - gts[L + Fl] + gts[Fl + 1];
    bool fvalid = f < Fl;
    float cf = fvalid ? (-gts[f + 1] - gts[Fl - f]) : 0.f;
#pragma unroll
    for (int i = 0; i < 32; ++i) {
        int s = sg + i * 4;
        float o;
        if (s >= L || !fvalid) {
            o = NEG_HUGE;
        } else {
            float lp = cb + cf - gts[s + 1] - gts[L - s]
                     + gts[s + f + 1] + gts[L - 1 - s + Fl - f];
            o = lp + sv[i] - lse;
        }
        out[(b * S + s) * F + f] = o;
    }
}

extern "C" void kernel_launch(void* const* d_in, const int* in_sizes, int n_in,
                              void* d_out, int out_size, void* d_ws, size_t ws_size,
                              hipStream_t stream)
{
    const float* h   = (const float*)d_in[0];
    const float* m_  = (const float*)d_in[1];
    const float* tw1 = (const float*)d_in[2];
    const float* tb1 = (const float*)d_in[3];
    const float* tw2 = (const float*)d_in[4];
    const float* tb2 = (const float*)d_in[5];
    const float* fw1 = (const float*)d_in[6];
    const float* fb1 = (const float*)d_in[7];
    const float* fw2 = (const float*)d_in[8];
    const float* fb2 = (const float*)d_in[9];
    const float* fw3 = (const float*)d_in[10];
    const float* fb3 = (const float*)d_in[11];
    const int* tokl  = (const int*)d_in[13];
    const int* featl = (const int*)d_in[14];

    float* ws    = (float*)d_ws;
    float* gt    = ws;
    float* tw1t  = gt   + 1024;
    float* tw2t  = tw1t + N_T1;
    float* fw1t  = tw2t + N_T2;
    float* fw2t  = fw1t + N_F1;
    float* fw3t  = fw2t + N_F2;
    float* hh    = fw3t + N_F3;
    float* mm    = hh   + B * S * D;
    float* out   = (float*)d_out;

    k_prep<<<(PREP_TOTAL + 255) / 256, 256, 0, stream>>>(
        tw1, tw2, fw1, fw2, fw3, gt, tw1t, tw2t, fw1t, fw2t, fw3t);

    k_stacks<<<NFB + NTB, 256, 0, stream>>>(
        h, m_, tw1t, tb1, tw2t, tb2, fw1t, fb1, fw2t, fb2, fw3t, fb3, hh, mm);

    k_dist<<<B * (S / TS) * (F / TF), 256, 0, stream>>>(hh, mm, out);
    k_soft<<<B * (F / 64), 256, 0, stream>>>(gt, tokl, featl, out);
}

// Round 6
// 110.979 us; speedup vs baseline: 1.2443x; 1.0709x over previous
//
#include <hip/hip_runtime.h>
#include <cmath>

constexpr int B = 8, S = 128, F = 512, D = 256, FEAT = 80;
// Finite stand-in for -inf (see round-1 note: avoids nan in harness absmax).
#define NEG_HUGE (-3.0e38f)

typedef unsigned short u16;
typedef unsigned int u32;
typedef __attribute__((ext_vector_type(8))) short bf16x8;   // 8 bf16 = 4 VGPR
typedef __attribute__((ext_vector_type(4))) float f32x4;

// ---- bf16 split helpers ----
__device__ __forceinline__ u16 f2bf(float x) {
    u32 u = __float_as_uint(x);
    u32 r = (u + 0x7fffu + ((u >> 16) & 1u)) >> 16;   // RNE
    return (u16)r;
}
__device__ __forceinline__ float bf2f(u16 s) {
    return __uint_as_float(((u32)s) << 16);
}
__device__ __forceinline__ void split_store(float v, u16* __restrict__ hi,
                                            u16* __restrict__ lo, int idx) {
    u16 h = f2bf(v);
    hi[idx] = h;
    lo[idx] = f2bf(v - bf2f(h));
}

// ================= sizes =================
constexpr int PRF = F + 2;      // 514 padded feat rows
constexpr int PRH = S + 2;      // 130 padded text rows
constexpr int CIN_M = 96;       // FEAT=80 padded to 96

constexpr int N_G    = 1024;
constexpr int N_WT1  = 256 * 768;    // tw1 -> [256][768]
constexpr int N_WT2  = 256 * 256;
constexpr int N_WF1  = 256 * 288;    // fw1 -> [256][3*96]
constexpr int N_WF2  = 256 * 768;
constexpr int N_WF3  = 256 * 256;
constexpr int N_MHL  = B * PRF * CIN_M;   // 394752
constexpr int N_HHL  = B * PRH * D;       // 266240
constexpr int N_Y1P  = B * 2 * D;         // zero pad rows of y1
constexpr int PREP_TOTAL = N_G + N_WT1 + N_WT2 + N_WF1 + N_WF2 + N_WF3
                         + N_MHL + N_HHL + N_Y1P;

// ================= prep: gamma + weight/input conversion =================
__device__ __forceinline__ void wconv(const float* __restrict__ w,
                                      u16* __restrict__ oh, u16* __restrict__ ol,
                                      int I, int TAPS, int CINP, int idx) {
    int KTOT = TAPS * CINP;
    int o = idx / KTOT, kk = idx % KTOT;
    int tap = kk / CINP, ci = kk % CINP;
    float v = (ci < I) ? w[(o * I + ci) * TAPS + tap] : 0.f;
    split_store(v, oh, ol, idx);
}

__global__ __launch_bounds__(256) void k_prep(
    const float* __restrict__ m, const float* __restrict__ h,
    const float* __restrict__ tw1, const float* __restrict__ tw2,
    const float* __restrict__ fw1, const float* __restrict__ fw2,
    const float* __restrict__ fw3,
    float* __restrict__ gt,
    u16* __restrict__ WT1h, u16* __restrict__ WT1l,
    u16* __restrict__ WT2h, u16* __restrict__ WT2l,
    u16* __restrict__ WF1h, u16* __restrict__ WF1l,
    u16* __restrict__ WF2h, u16* __restrict__ WF2l,
    u16* __restrict__ WF3h, u16* __restrict__ WF3l,
    u16* __restrict__ Mh, u16* __restrict__ Ml,
    u16* __restrict__ Hh, u16* __restrict__ Hl,
    u16* __restrict__ Y1h, u16* __restrict__ Y1l)
{
    int idx = blockIdx.x * 256 + threadIdx.x;
    if (idx < N_G) { gt[idx] = (float)lgamma((double)idx); return; }
    idx -= N_G;
    if (idx < N_WT1) { wconv(tw1, WT1h, WT1l, 256, 3, 256, idx); return; }
    idx -= N_WT1;
    if (idx < N_WT2) { wconv(tw2, WT2h, WT2l, 256, 1, 256, idx); return; }
    idx -= N_WT2;
    if (idx < N_WF1) { wconv(fw1, WF1h, WF1l,  80, 3, CIN_M, idx); return; }
    idx -= N_WF1;
    if (idx < N_WF2) { wconv(fw2, WF2h, WF2l, 256, 3, 256, idx); return; }
    idx -= N_WF2;
    if (idx < N_WF3) { wconv(fw3, WF3h, WF3l, 256, 1, 256, idx); return; }
    idx -= N_WF3;
    if (idx < N_MHL) {
        int ci = idx % CIN_M;
        int p  = (idx / CIN_M) % PRF;
        int b  = idx / (CIN_M * PRF);
        float v = (p >= 1 && p <= F && ci < FEAT)
                ? m[(b * F + (p - 1)) * FEAT + ci] : 0.f;
        split_store(v, Mh, Ml, idx);
        return;
    }
    idx -= N_MHL;
    if (idx < N_HHL) {
        int ci = idx % D;
        int p  = (idx / D) % PRH;
        int b  = idx / (D * PRH);
        float v = (p >= 1 && p <= S) ? h[(b * S + (p - 1)) * D + ci] : 0.f;
        split_store(v, Hh, Hl, idx);
        return;
    }
    idx -= N_HHL;
    if (idx < N_Y1P) {   // zero the halo rows of y1 (rows 0 and PRF-1 per batch)
        int ci = idx % D;
        int which = (idx / D) & 1;
        int b = idx / (2 * D);
        int row = b * PRF + (which ? (PRF - 1) : 0);
        Y1h[row * D + ci] = 0;
        Y1l[row * D + ci] = 0;
    }
}

// ================= generic MFMA conv tile: 16 pos x 64 cout per wave =================
// A: act[row][k], row = pos (+halo offset), k = tap*CINP+ci, hi/lo planes.
// W: B^T layout [co][tap*CINP+ci], hi/lo planes.
// D = A*W^T via mfma_16x16x32_bf16, split 3-term for fp32-grade accuracy.
template<int CINP, int TAPS, bool RELU, bool OUT_HL>
__device__ __forceinline__ void conv_tile(
    const u16* __restrict__ Ah, const u16* __restrict__ Al, int arowbase,
    const u16* __restrict__ Wh, const u16* __restrict__ Wl,
    const float* __restrict__ bias, int co0,
    float* __restrict__ outF, u16* __restrict__ Oh, u16* __restrict__ Ol,
    int orowbase)
{
    constexpr int KTOT = TAPS * CINP;
    constexpr int KSTEPS = KTOT / 32;
    constexpr int KPT = CINP / 32;     // k-steps per tap
    const int l  = threadIdx.x & 63;
    const int lr = l & 15;
    const int kg = l >> 4;

    f32x4 acc0 = {0.f, 0.f, 0.f, 0.f};
    f32x4 acc1 = acc0, acc2 = acc0, acc3 = acc0;

    const u16* arh = Ah + (arowbase + lr) * CINP + kg * 8;
    const u16* arl = Al + (arowbase + lr) * CINP + kg * 8;
    const u16* wh  = Wh + (co0 + lr) * KTOT + kg * 8;
    const u16* wl  = Wl + (co0 + lr) * KTOT + kg * 8;

#pragma unroll
    for (int kb = 0; kb < KSTEPS; ++kb) {
        const int tap = kb / KPT;
        const int aoff = tap * CINP + (kb % KPT) * 32;
        bf16x8 ah = *(const bf16x8*)(arh + aoff);
        bf16x8 al = *(const bf16x8*)(arl + aoff);
        const int wk = kb * 32;
        bf16x8 b0h = *(const bf16x8*)(wh + 0 * 16 * KTOT + wk);
        bf16x8 b0l = *(const bf16x8*)(wl + 0 * 16 * KTOT + wk);
        bf16x8 b1h = *(const bf16x8*)(wh + 1 * 16 * KTOT + wk);
        bf16x8 b1l = *(const bf16x8*)(wl + 1 * 16 * KTOT + wk);
        bf16x8 b2h = *(const bf16x8*)(wh + 2 * 16 * KTOT + wk);
        bf16x8 b2l = *(const bf16x8*)(wl + 2 * 16 * KTOT + wk);
        bf16x8 b3h = *(const bf16x8*)(wh + 3 * 16 * KTOT + wk);
        bf16x8 b3l = *(const bf16x8*)(wl + 3 * 16 * KTOT + wk);
        acc0 = __builtin_amdgcn_mfma_f32_16x16x32_bf16(ah, b0h, acc0, 0, 0, 0);
        acc1 = __builtin_amdgcn_mfma_f32_16x16x32_bf16(ah, b1h, acc1, 0, 0, 0);
        acc2 = __builtin_amdgcn_mfma_f32_16x16x32_bf16(ah, b2h, acc2, 0, 0, 0);
        acc3 = __builtin_amdgcn_mfma_f32_16x16x32_bf16(ah, b3h, acc3, 0, 0, 0);
        acc0 = __builtin_amdgcn_mfma_f32_16x16x32_bf16(ah, b0l, acc0, 0, 0, 0);
        acc1 = __builtin_amdgcn_mfma_f32_16x16x32_bf16(ah, b1l, acc1, 0, 0, 0);
        acc2 = __builtin_amdgcn_mfma_f32_16x16x32_bf16(ah, b2l, acc2, 0, 0, 0);
        acc3 = __builtin_amdgcn_mfma_f32_16x16x32_bf16(ah, b3l, acc3, 0, 0, 0);
        acc0 = __builtin_amdgcn_mfma_f32_16x16x32_bf16(al, b0h, acc0, 0, 0, 0);
        acc1 = __builtin_amdgcn_mfma_f32_16x16x32_bf16(al, b1h, acc1, 0, 0, 0);
        acc2 = __builtin_amdgcn_mfma_f32_16x16x32_bf16(al, b2h, acc2, 0, 0, 0);
        acc3 = __builtin_amdgcn_mfma_f32_16x16x32_bf16(al, b3h, acc3, 0, 0, 0);
    }

    const int orow = orowbase + kg * 4;
    const f32x4* accs[4] = { &acc0, &acc1, &acc2, &acc3 };
#pragma unroll
    for (int nt = 0; nt < 4; ++nt) {
        int co = co0 + nt * 16 + lr;
        float bv = bias[co];
#pragma unroll
        for (int r = 0; r < 4; ++r) {
            float v = (*accs[nt])[r] + bv;
            if (RELU) v = fmaxf(v, 0.f);
            int o = (orow + r) * 256 + co;
            if (OUT_HL) split_store(v, Oh, Ol, o);
            else        outF[o] = v;
        }
    }
}

// ---- kernel A: f1 (1024 blocks) + t1 (256 blocks) ----
__global__ __launch_bounds__(64, 1) void k_convA(
    const u16* __restrict__ Mh, const u16* __restrict__ Ml,
    const u16* __restrict__ Hh, const u16* __restrict__ Hl,
    const u16* __restrict__ WF1h, const u16* __restrict__ WF1l,
    const u16* __restrict__ WT1h, const u16* __restrict__ WT1l,
    const float* __restrict__ fb1, const float* __restrict__ tb1,
    u16* __restrict__ Y1h, u16* __restrict__ Y1l,
    u16* __restrict__ X1h, u16* __restrict__ X1l)
{
    int bid = blockIdx.x;
    if (bid < 1024) {   // f1: relu(conv3(m)) -> y1 (padded rows)
        int co0 = (bid & 3) * 64;
        int p0  = ((bid >> 2) & 31) * 16;
        int b   = bid >> 7;
        conv_tile<CIN_M, 3, true, true>(Mh, Ml, b * PRF + p0, WF1h, WF1l, fb1, co0,
                                        nullptr, Y1h, Y1l, b * PRF + p0 + 1);
    } else {            // t1: relu(conv3(h)) -> x1 (unpadded)
        int i = bid - 1024;
        int co0 = (i & 3) * 64;
        int p0  = ((i >> 2) & 7) * 16;
        int b   = i >> 5;
        conv_tile<D, 3, true, true>(Hh, Hl, b * PRH + p0, WT1h, WT1l, tb1, co0,
                                    nullptr, X1h, X1l, b * S + p0);
    }
}

// ---- kernel B: f2 (1024 blocks) ----
__global__ __launch_bounds__(64, 1) void k_convB(
    const u16* __restrict__ Y1h, const u16* __restrict__ Y1l,
    const u16* __restrict__ WF2h, const u16* __restrict__ WF2l,
    const float* __restrict__ fb2,
    u16* __restrict__ Y2h, u16* __restrict__ Y2l)
{
    int bid = blockIdx.x;
    int co0 = (bid & 3) * 64;
    int p0  = ((bid >> 2) & 31) * 16;
    int b   = bid >> 7;
    conv_tile<D, 3, true, true>(Y1h, Y1l, b * PRF + p0, WF2h, WF2l, fb2, co0,
                                nullptr, Y2h, Y2l, b * F + p0);
}

// ---- kernel C: f3 (1024 blocks) + t2 (256 blocks) ----
__global__ __launch_bounds__(64, 1) void k_convC(
    const u16* __restrict__ Y2h, const u16* __restrict__ Y2l,
    const u16* __restrict__ X1h, const u16* __restrict__ X1l,
    const u16* __restrict__ WF3h, const u16* __restrict__ WF3l,
    const u16* __restrict__ WT2h, const u16* __restrict__ WT2l,
    const float* __restrict__ fb3, const float* __restrict__ tb2,
    float* __restrict__ mm, float* __restrict__ hh)
{
    int bid = blockIdx.x;
    if (bid < 1024) {   // f3: conv1(y2) -> mm fp32
        int co0 = (bid & 3) * 64;
        int p0  = ((bid >> 2) & 31) * 16;
        int b   = bid >> 7;
        conv_tile<D, 1, false, false>(Y2h, Y2l, b * F + p0, WF3h, WF3l, fb3, co0,
                                      mm, nullptr, nullptr, b * F + p0);
    } else {            // t2: conv1(x1) -> hh fp32
        int i = bid - 1024;
        int co0 = (i & 3) * 64;
        int p0  = ((i >> 2) & 7) * 16;
        int b   = i >> 5;
        conv_tile<D, 1, false, false>(X1h, X1l, b * S + p0, WT2h, WT2l, tb2, co0,
                                      hh, nullptr, nullptr, b * S + p0);
    }
}

// ---------------- pairwise L2 distance ----------------
constexpr int TS = 32, TF = 64, TK = 32;
__global__ __launch_bounds__(256) void k_dist(
    const float* __restrict__ hh, const float* __restrict__ mm,
    float* __restrict__ scores)
{
    __shared__ float As[TS][TK + 1];
    __shared__ float Bs[TF][TK + 1];
    int t = threadIdx.x;
    constexpr int nf = F / TF;
    constexpr int ns = S / TS;
    int b = blockIdx.x / (nf * ns);
    int rem = blockIdx.x % (nf * ns);
    int s0 = (rem / nf) * TS;
    int f0 = (rem % nf) * TF;
    int tx = t & 15, ty = t >> 4;

    float c[2][4] = {};
    for (int k0 = 0; k0 < D; k0 += TK) {
        {
            int r = t / 8, c4 = (t % 8) * 4;
            float4 v = *(const float4*)&hh[(b * S + s0 + r) * D + k0 + c4];
            As[r][c4] = v.x; As[r][c4 + 1] = v.y; As[r][c4 + 2] = v.z; As[r][c4 + 3] = v.w;
        }
#pragma unroll
        for (int half = 0; half < 2; ++half) {
            int rr = half * 32 + t / 8, c4 = (t % 8) * 4;
            float4 v = *(const float4*)&mm[(b * F + f0 + rr) * D + k0 + c4];
            Bs[rr][c4] = v.x; Bs[rr][c4 + 1] = v.y; Bs[rr][c4 + 2] = v.z; Bs[rr][c4 + 3] = v.w;
        }
        __syncthreads();
#pragma unroll
        for (int k = 0; k < TK; ++k) {
            float a0 = As[ty * 2 + 0][k];
            float a1 = As[ty * 2 + 1][k];
            float b0 = Bs[tx * 4 + 0][k];
            float b1 = Bs[tx * 4 + 1][k];
            float b2 = Bs[tx * 4 + 2][k];
            float b3 = Bs[tx * 4 + 3][k];
            float d;
            d = a0 - b0; c[0][0] = fmaf(d, d, c[0][0]);
            d = a0 - b1; c[0][1] = fmaf(d, d, c[0][1]);
            d = a0 - b2; c[0][2] = fmaf(d, d, c[0][2]);
            d = a0 - b3; c[0][3] = fmaf(d, d, c[0][3]);
            d = a1 - b0; c[1][0] = fmaf(d, d, c[1][0]);
            d = a1 - b1; c[1][1] = fmaf(d, d, c[1][1]);
            d = a1 - b2; c[1][2] = fmaf(d, d, c[1][2]);
            d = a1 - b3; c[1][3] = fmaf(d, d, c[1][3]);
        }
        __syncthreads();
    }
#pragma unroll
    for (int i = 0; i < 2; ++i) {
        int s = s0 + ty * 2 + i;
        float4 v;
        v.x = -sqrtf(fmaxf(c[i][0], 0.f));
        v.y = -sqrtf(fmaxf(c[i][1], 0.f));
        v.z = -sqrtf(fmaxf(c[i][2], 0.f));
        v.w = -sqrtf(fmaxf(c[i][3], 0.f));
        *(float4*)&scores[(b * S + s) * F + f0 + tx * 4] = v;
    }
}

// ---------------- softmax over S + beta-binomial prior (in-place on d_out) ----------------
__global__ __launch_bounds__(256) void k_soft(
    const float* __restrict__ gt,
    const int* __restrict__ tok_len, const int* __restrict__ feat_len,
    float* __restrict__ out)
{
    __shared__ float gts[1024];
    __shared__ float red[256];
    int t = threadIdx.x;
    int b = blockIdx.x / (F / 64);
    int f0 = (blockIdx.x % (F / 64)) * 64;
    int fi = t & 63, sg = t >> 6;
    int f = f0 + fi;
    for (int i = t; i < 1024; i += 256) gts[i] = gt[i];
    int L = tok_len[b], Fl = feat_len[b];

    float sv[32];
    float mx = -INFINITY;
#pragma unroll
    for (int i = 0; i < 32; ++i) {
        int s = sg + i * 4;
        float v = out[(b * S + s) * F + f];
        if (s >= L) v = -INFINITY;
        sv[i] = v;
        mx = fmaxf(mx, v);
    }
    red[t] = mx;
    __syncthreads();
    float m = fmaxf(fmaxf(red[fi], red[64 + fi]), fmaxf(red[128 + fi], red[192 + fi]));
    __syncthreads();
    float sum = 0.f;
#pragma unroll
    for (int i = 0; i < 32; ++i) sum += expf(sv[i] - m);
    red[t] = sum;
    __syncthreads();
    float tot = red[fi] + red[64 + fi] + red[128 + fi] + red[192 + fi];
    float lse = m + logf(tot);

    float cb = gts[L] - gts[L + Fl] + gts[Fl + 1];
    bool fvalid = f < Fl;
    float cf = fvalid ? (-gts[f + 1] - gts[Fl - f]) : 0.f;
#pragma unroll
    for (int i = 0; i < 32; ++i) {
        int s = sg + i * 4;
        float o;
        if (s >= L || !fvalid) {
            o = NEG_HUGE;
        } else {
            float lp = cb + cf - gts[s + 1] - gts[L - s]
                     + gts[s + f + 1] + gts[L - 1 - s + Fl - f];
            o = lp + sv[i] - lse;
        }
        out[(b * S + s) * F + f] = o;
    }
}

extern "C" void kernel_launch(void* const* d_in, const int* in_sizes, int n_in,
                              void* d_out, int out_size, void* d_ws, size_t ws_size,
                              hipStream_t stream)
{
    const float* h   = (const float*)d_in[0];
    const float* m_  = (const float*)d_in[1];
    const float* tw1 = (const float*)d_in[2];
    const float* tb1 = (const float*)d_in[3];
    const float* tw2 = (const float*)d_in[4];
    const float* tb2 = (const float*)d_in[5];
    const float* fw1 = (const float*)d_in[6];
    const float* fb1 = (const float*)d_in[7];
    const float* fw2 = (const float*)d_in[8];
    const float* fb2 = (const float*)d_in[9];
    const float* fw3 = (const float*)d_in[10];
    const float* fb3 = (const float*)d_in[11];
    const int* tokl  = (const int*)d_in[13];
    const int* featl = (const int*)d_in[14];

    char* base = (char*)d_ws;
    size_t off = 0;
    auto alloc = [&](size_t bytes) -> char* {
        size_t a = (off + 255) & ~(size_t)255;
        off = a + bytes;
        return base + a;
    };

    float* gt  = (float*)alloc(N_G * 4);
    u16* WT1h = (u16*)alloc(N_WT1 * 2); u16* WT1l = (u16*)alloc(N_WT1 * 2);
    u16* WT2h = (u16*)alloc(N_WT2 * 2); u16* WT2l = (u16*)alloc(N_WT2 * 2);
    u16* WF1h = (u16*)alloc(N_WF1 * 2); u16* WF1l = (u16*)alloc(N_WF1 * 2);
    u16* WF2h = (u16*)alloc(N_WF2 * 2); u16* WF2l = (u16*)alloc(N_WF2 * 2);
    u16* WF3h = (u16*)alloc(N_WF3 * 2); u16* WF3l = (u16*)alloc(N_WF3 * 2);
    u16* Mh   = (u16*)alloc(N_MHL * 2); u16* Ml   = (u16*)alloc(N_MHL * 2);
    u16* Hh   = (u16*)alloc(N_HHL * 2); u16* Hl   = (u16*)alloc(N_HHL * 2);
    u16* Y1h  = (u16*)alloc(B * PRF * D * 2); u16* Y1l = (u16*)alloc(B * PRF * D * 2);
    u16* Y2h  = (u16*)alloc(B * F * D * 2);   u16* Y2l = (u16*)alloc(B * F * D * 2);
    u16* X1h  = (u16*)alloc(B * S * D * 2);   u16* X1l = (u16*)alloc(B * S * D * 2);
    float* mm = (float*)alloc(B * F * D * 4);
    float* hh = (float*)alloc(B * S * D * 4);
    float* out = (float*)d_out;

    k_prep<<<(PREP_TOTAL + 255) / 256, 256, 0, stream>>>(
        m_, h, tw1, tw2, fw1, fw2, fw3, gt,
        WT1h, WT1l, WT2h, WT2l, WF1h, WF1l, WF2h, WF2l, WF3h, WF3l,
        Mh, Ml, Hh, Hl, Y1h, Y1l);

    k_convA<<<1280, 64, 0, stream>>>(Mh, Ml, Hh, Hl, WF1h, WF1l, WT1h, WT1l,
                                     fb1, tb1, Y1h, Y1l, X1h, X1l);
    k_convB<<<1024, 64, 0, stream>>>(Y1h, Y1l, WF2h, WF2l, fb2, Y2h, Y2l);
    k_convC<<<1280, 64, 0, stream>>>(Y2h, Y2l, X1h, X1l, WF3h, WF3l, WT2h, WT2l,
                                     fb3, tb2, mm, hh);

    k_dist<<<B * (S / TS) * (F / TF), 256, 0, stream>>>(hh, mm, out);
    k_soft<<<B * (F / 64), 256, 0, stream>>>(gt, tokl, featl, out);
}